// Round 16
// baseline (59.495 us; speedup 1.0000x reference)
//
#include <hip/hip_runtime.h>

typedef int i32x4 __attribute__((ext_vector_type(4)));
typedef float f32x4 __attribute__((ext_vector_type(4)));

#define D_DIM 256
// base-2 scale: sv2 = acc * (1/T) * log2(e) = acc * 2 * 1.442695...
#define C2 2.88539008f
#define LN2 0.69314718f

// Fragment-native fp8 L-layout: byte(row, k) at
//   ((row>>4)*8 + (k>>5))*512 + (row&15)*32 + (k&31)
// One MFMA fragment (16 rows x 32 k) = 512 CONTIGUOUS bytes; a wave's
// 64 lanes x 8B tile it exactly (lane reads (lane&15)*32 + (lane>>4)*8).

// ---------------- Kernel 1: L2-normalize -> fp8 e4m3 L-layout R -------------
__global__ __launch_bounds__(256) void k_normalize(const float* __restrict__ ei,
                                                   const float* __restrict__ ej,
                                                   unsigned char* __restrict__ R,
                                                   unsigned* __restrict__ ticket,
                                                   int B) {
  if (blockIdx.x == 0 && threadIdx.x == 0) *ticket = 0u;  // per-call reset
  const int w = threadIdx.x >> 6, lane = threadIdx.x & 63;
  const int row = blockIdx.x * 16 + w * 4 + (lane >> 4);
  const int kq = lane & 15;  // owns k in [kq*16, kq*16+16)
  const float* src = (row < B) ? (ei + (size_t)row * D_DIM)
                               : (ej + (size_t)(row - B) * D_DIM);
  const float4* s4 = (const float4*)src + kq * 4;
  float4 v0 = s4[0], v1 = s4[1], v2 = s4[2], v3 = s4[3];
  float ss = v0.x*v0.x + v0.y*v0.y + v0.z*v0.z + v0.w*v0.w
           + v1.x*v1.x + v1.y*v1.y + v1.z*v1.z + v1.w*v1.w
           + v2.x*v2.x + v2.y*v2.y + v2.z*v2.z + v2.w*v2.w
           + v3.x*v3.x + v3.y*v3.y + v3.z*v3.z + v3.w*v3.w;
#pragma unroll
  for (int d = 1; d < 16; d <<= 1) ss += __shfl_xor(ss, d, 64);  // 16-group
  const float s = 1.0f / fmaxf(sqrtf(ss), 1e-12f);
  int q0 = __builtin_amdgcn_cvt_pk_fp8_f32(v0.x*s, v0.y*s, 0, 0);
  q0     = __builtin_amdgcn_cvt_pk_fp8_f32(v0.z*s, v0.w*s, q0, 1);
  int q1 = __builtin_amdgcn_cvt_pk_fp8_f32(v1.x*s, v1.y*s, 0, 0);
  q1     = __builtin_amdgcn_cvt_pk_fp8_f32(v1.z*s, v1.w*s, q1, 1);
  int q2 = __builtin_amdgcn_cvt_pk_fp8_f32(v2.x*s, v2.y*s, 0, 0);
  q2     = __builtin_amdgcn_cvt_pk_fp8_f32(v2.z*s, v2.w*s, q2, 1);
  int q3 = __builtin_amdgcn_cvt_pk_fp8_f32(v3.x*s, v3.y*s, 0, 0);
  q3     = __builtin_amdgcn_cvt_pk_fp8_f32(v3.z*s, v3.w*s, q3, 1);
  i32x4 o = {q0, q1, q2, q3};
  // L-layout: kt = kq>>1, 16B half = kq&1
  const size_t idx = (((size_t)(row >> 4) * 8 + (kq >> 1)) * 16 + (row & 15)) * 32
                   + (size_t)(kq & 1) * 16;
  *(i32x4*)(R + idx) = o;
}

// ---------------- Kernel 2: register-resident symmetric sim GEMM ------------
// Upper-tri 128x128 tiles (bi <= bj), 4 waves (2x2), wave quadrant 64x64.
// NO LDS, NO barriers: fp8 K=256 -> ALL fragments fit in registers
// (A 64 + B 64 VGPR + acc 64 AGPR). Burst-issue 64 coalesced 8B frag loads
// (512B contiguous per wave-load, L-layout), ONE vmcnt(0) + sched_barrier(0)
// (loads can't cross the asm memory clobber; MFMAs can't hoist above it,
// rule #18), then 128 register-only MFMAs. Latency exposed once per wave,
// hidden by 8 independent waves/CU (2 blocks/CU at (256,2)).
__global__ __launch_bounds__(256, 2) void k_simgemm(const unsigned char* __restrict__ R,
                                                    float* __restrict__ rowPartial,
                                                    float* __restrict__ simTgt,
                                                    int N) {
  const int tid = threadIdx.x;
  const int w = tid >> 6, lane = tid & 63;
  const int wr = w >> 1, wc = w & 1;
  const int c15 = lane & 15, g = lane >> 4;
  const int half = N >> 1;

  // decode linear block id -> upper-triangular (bi, bj), bi <= bj
  const int T = N / 128;  // 64
  const int t = blockIdx.x;
  int bi = (int)(((float)(2 * T + 1) -
                  sqrtf((float)((2 * T + 1) * (2 * T + 1) - 8 * t))) * 0.5f);
  while (bi > 0 && t < bi * (2 * T - bi + 1) / 2) --bi;
  while (t >= (bi + 1) * (2 * T - bi) / 2) ++bi;
  const int bj = bi + (t - bi * (2 * T - bi + 1) / 2);
  const int brow = bi * 128, bcol = bj * 128;
  const bool offdiag = (bi != bj);

  // burst-load ALL fragments: a[m][kt], b[n][kt] (8B each lane)
  const size_t laneOff = (size_t)c15 * 32 + (size_t)g * 8;
  const char* Ab = (const char*)R + ((size_t)(brow >> 4) + wr * 4) * 4096 + laneOff;
  const char* Bb = (const char*)R + ((size_t)(bcol >> 4) + wc * 4) * 4096 + laneOff;
  long a[4][8], b[4][8];
#pragma unroll
  for (int m = 0; m < 4; ++m)
#pragma unroll
    for (int kt = 0; kt < 8; ++kt)
      a[m][kt] = *(const long*)(Ab + (size_t)m * 4096 + (size_t)kt * 512);
#pragma unroll
  for (int n = 0; n < 4; ++n)
#pragma unroll
    for (int kt = 0; kt < 8; ++kt)
      b[n][kt] = *(const long*)(Bb + (size_t)n * 4096 + (size_t)kt * 512);

  asm volatile("s_waitcnt vmcnt(0)" ::: "memory");
  __builtin_amdgcn_sched_barrier(0);

  f32x4 acc[4][4];
#pragma unroll
  for (int m = 0; m < 4; ++m)
#pragma unroll
    for (int n = 0; n < 4; ++n) acc[m][n] = (f32x4){0.f, 0.f, 0.f, 0.f};
#pragma unroll
  for (int kt = 0; kt < 8; ++kt)
#pragma unroll
    for (int m = 0; m < 4; ++m)
#pragma unroll
      for (int n = 0; n < 4; ++n)
        acc[m][n] = __builtin_amdgcn_mfma_f32_16x16x32_fp8_fp8(
            a[m][kt], b[n][kt], acc[m][n], 0, 0, 0);

  // epilogue (base-2): mask diag, capture targets, exp2, row-dir sums
  // (over tile cols) + col-dir sums (over rows, symmetry). R13's proven
  // rowPartial slot scheme (atomics regressed in R15 -- reverted).
  float cs4[4] = {0.f, 0.f, 0.f, 0.f};
#pragma unroll
  for (int m = 0; m < 4; ++m) {
#pragma unroll
    for (int j = 0; j < 4; ++j) {
      const int gr = brow + wr * 64 + m * 16 + g * 4 + j;
      const int tgt = (gr < half) ? gr + half : gr - half;
      float rs = 0.f;
#pragma unroll
      for (int n = 0; n < 4; ++n) {
        const int gc = bcol + wc * 64 + n * 16 + c15;
        const float sv2 = acc[m][n][j] * C2;
        const float ev = (gr == gc) ? 0.f : __builtin_amdgcn_exp2f(sv2);
        if (gc == tgt) {                  // involution: also gr == tgt(gc)
          simTgt[gr] = sv2;
          if (offdiag) simTgt[gc] = sv2;  // sim symmetric
        }
        rs += ev;
        cs4[n] += ev;
      }
#pragma unroll
      for (int d = 1; d < 16; d <<= 1) rs += __shfl_xor(rs, d, 64);
      if (c15 == 0)
        rowPartial[(size_t)(bj * 2 + wc) * N + gr] = rs;
    }
  }
  if (offdiag) {  // column block receives row-sums of the transposed tile
#pragma unroll
    for (int n = 0; n < 4; ++n) {
      float c = cs4[n];
      c += __shfl_xor(c, 16, 64);
      c += __shfl_xor(c, 32, 64);
      if (g == 0)
        rowPartial[(size_t)(bi * 2 + wr) * N + (bcol + wc * 64 + n * 16 + c15)] = c;
    }
  }
}

// ---------------- Kernel 3: row logsumexp-target + deterministic final mean --
__global__ __launch_bounds__(256) void k_rowreduce(const float* __restrict__ rowPartial,
                                                   const float* __restrict__ simTgt,
                                                   float* __restrict__ blockOut,
                                                   unsigned* __restrict__ ticket,
                                                   float* __restrict__ out, int N) {
  const int lane = threadIdx.x & 63;   // row within this block's 64
  const int q = threadIdx.x >> 6;      // partial-chunk 0..3
  const int row = blockIdx.x * 64 + lane;
  float part = 0.f;
#pragma unroll 8
  for (int c = q * 32; c < q * 32 + 32; ++c)
    part += rowPartial[(size_t)c * N + row];
  __shared__ float red[4][64];
  __shared__ int isLast;
  red[q][lane] = part;
  __syncthreads();
  if (threadIdx.x < 64) {
    const float denom = red[0][lane] + red[1][lane] + red[2][lane] + red[3][lane];
    // v_log_f32 = log2; loss = (log2(denom) - sv2) * ln2
    float lossr = (__builtin_amdgcn_logf(denom) - simTgt[row]) * LN2;
#pragma unroll
    for (int d = 32; d; d >>= 1) lossr += __shfl_xor(lossr, d, 64);
    if (threadIdx.x == 0) {
      // device-scope RMW write: coherent across XCDs, deterministic value
      atomicExch(&blockOut[blockIdx.x], lossr);
      isLast = (atomicAdd(ticket, 1u) == gridDim.x - 1);
    }
  }
  __syncthreads();
  if (isLast && threadIdx.x < 64) {
    // coherent read of all 128 block sums via atomic RMW (+0.0f), fixed order
    float v = atomicAdd(&blockOut[threadIdx.x], 0.0f) +
              atomicAdd(&blockOut[64 + threadIdx.x], 0.0f);
#pragma unroll
    for (int d = 32; d; d >>= 1) v += __shfl_xor(v, d, 64);
    if (threadIdx.x == 0) out[0] = v / (float)N;
  }
}

extern "C" void kernel_launch(void* const* d_in, const int* in_sizes, int n_in,
                              void* d_out, int out_size, void* d_ws, size_t ws_size,
                              hipStream_t stream) {
  const float* ei = (const float*)d_in[0];
  const float* ej = (const float*)d_in[1];
  const int B = in_sizes[0] / D_DIM;  // 4096
  const int N = 2 * B;                // 8192

  char* ws = (char*)d_ws;
  unsigned char* R = (unsigned char*)ws;                                  // N*256 = 2MB (fp8, L-layout)
  float* rowPartial = (float*)(ws + (size_t)N * D_DIM);                   // 128*N*4 = 4MB
  float* simTgt     = (float*)(ws + (size_t)N * D_DIM + (size_t)128 * N * 4);  // N*4
  float* blockOut   = (float*)((char*)simTgt + (size_t)N * 4);            // 128*4
  unsigned* ticket  = (unsigned*)((char*)blockOut + 128 * 4);             // 4B

  k_normalize<<<N / 16, 256, 0, stream>>>(ei, ej, R, ticket, B);
  const int T = N / 128;
  k_simgemm<<<T * (T + 1) / 2, 256, 0, stream>>>(R, rowPartial, simTgt, N);
  k_rowreduce<<<N / 64, 256, 0, stream>>>(rowPartial, simTgt, blockOut, ticket,
                                          (float*)d_out, N);
}